// Round 20
// baseline (344.673 us; speedup 1.0000x reference)
//
#include <hip/hip_runtime.h>
#include <hip/hip_bf16.h>

// GCN: 3x GCNConv(H=64) + global mean pool + linear head.
// Round 19 -> 20:
//  (1) SBS 512->256: p1 counts 512 buckets (2/thread), p2 grid 196->391
//      blocks (the build's occupancy bottleneck).
//  (2) csr stores src<<5 (pre-scaled row index): gather addr = add only.
//  (3) rows padded to x8; gather processes ONE row in groups of 8 edges
//      (4 packed-uint loads), no pair coupling, no masks, 2-deep pipeline.
// bf16 buffers, packed-uint 2-edges/load, p1 staged writes all retained.

#define WS_ALIGN(x) (((x) + 255) & ~size_t(255))
#define NB 32            // dst rows per gather block
#define RPW (NB / 4)     // rows per wave = 8
#define USH 17
#define BKTMAX 512       // max superblocks (N <= 131072 @ SBS=256)
#define SBS 256          // dsts per superblock
#define NCHUNK 8
#define CSH 14           // chunk = src >> 14 (locality sort key inside rows)
#define SBKEYS (SBS * NCHUNK)   // 2048
#define P1T 2048
#define PADGAP 1792      // per-superblock csr slack: 256 rows x up to 7 pads

__device__ __forceinline__ unsigned short f2bf(float f) {
    union { float f; unsigned u; } t;
    t.f = f;
    unsigned r = t.u + 0x7FFF + ((t.u >> 16) & 1);   // round-to-nearest-even
    return (unsigned short)(r >> 16);
}
__device__ __forceinline__ float bfLo(unsigned v) {
    union { unsigned u; float f; } t;
    t.u = v << 16;
    return t.f;
}
__device__ __forceinline__ float bfHi(unsigned v) {
    union { unsigned u; float f; } t;
    t.u = v & 0xFFFF0000u;
    return t.f;
}

// zero bucket counts/cursors, pool accumulators, zero-row (node n), xs[n]
__global__ __launch_bounds__(256) void k_zero(int g, int n, int* bucketCnt,
                                              int* gCursor, float* xs,
                                              unsigned short* bufA,
                                              unsigned short* bufB,
                                              float* gsum, float* gcnt) {
    int i = blockIdx.x * blockDim.x + threadIdx.x;
    if (i < BKTMAX) { bucketCnt[i] = 0; gCursor[i] = 0; }
    if (i < g) { gsum[i] = 0.f; gcnt[i] = 0.f; }
    if (i < 64) {
        bufA[(size_t)n * 64 + i] = 0;
        bufB[(size_t)n * 64 + i] = 0;
    }
    if (i == 0) xs[n] = 0.f;
}

__global__ __launch_bounds__(256) void k_cnt1(int e, const int* __restrict__ dst,
                                              int* __restrict__ bucketCnt) {
    __shared__ int c[BKTMAX];
    int tid = threadIdx.x;
    c[tid] = 0; c[tid + 256] = 0;
    __syncthreads();
    int base = blockIdx.x * P1T;
#pragma unroll
    for (int q = 0; q < P1T / 256; ++q) {
        int i = base + q * 256 + tid;
        if (i < e) atomicAdd(&c[dst[i] >> 8], 1);
    }
    __syncthreads();
    if (c[tid] > 0) atomicAdd(&bucketCnt[tid], c[tid]);
    if (c[tid + 256] > 0) atomicAdd(&bucketCnt[tid + 256], c[tid + 256]);
}

// scan up to 512 bucket counts (2/thread) -> bucketStart[nbkt+1]
__global__ __launch_bounds__(256) void k_scanB(int nbkt, int e,
                                               const int* __restrict__ bucketCnt,
                                               int* __restrict__ bucketStart) {
    __shared__ int sd[256];
    int tid = threadIdx.x;
    int i0 = tid * 2;
    int v0 = (i0 < nbkt) ? bucketCnt[i0] : 0;
    int v1 = (i0 + 1 < nbkt) ? bucketCnt[i0 + 1] : 0;
    int ts = v0 + v1;
    sd[tid] = ts;
    __syncthreads();
    for (int off = 1; off < 256; off <<= 1) {
        int t = (tid >= off) ? sd[tid - off] : 0;
        __syncthreads();
        sd[tid] += t;
        __syncthreads();
    }
    int excl = sd[tid] - ts;
    if (i0 < nbkt) bucketStart[i0] = excl;
    if (i0 + 1 < nbkt) bucketStart[i0 + 1] = excl + v0;
    if (tid == 0) bucketStart[nbkt] = e;
}

// p1: tile sort by superblock (512 buckets), contiguous run writes
__global__ __launch_bounds__(256) void k_p1(int e, const int* __restrict__ src,
                                            const int* __restrict__ dst,
                                            const int* __restrict__ bucketStart,
                                            int* __restrict__ gCursor,
                                            int* __restrict__ pkbuf) {
    __shared__ int cnt[BKTMAX], exc[BKTMAX], cur[BKTMAX], bb[BKTMAX];
    __shared__ int sd[256];
    __shared__ int stage[P1T];
    __shared__ unsigned short stgb[P1T];
    int tid = threadIdx.x;
    cnt[tid] = 0; cnt[tid + 256] = 0;
    __syncthreads();
    int base = blockIdx.x * P1T;
    int m = e - base; if (m > P1T) m = P1T;
    int pk8[P1T / 256];
    int b8[P1T / 256];
#pragma unroll
    for (int q = 0; q < P1T / 256; ++q) {
        int li = q * 256 + tid;
        if (li < m) {
            int d = dst[base + li];
            int s = src[base + li];
            int b = d >> 8;
            b8[q] = b;
            pk8[q] = ((d & (SBS - 1)) << USH) | s;
            atomicAdd(&cnt[b], 1);
        }
    }
    __syncthreads();
    int i0 = tid * 2;
    int c0 = cnt[i0], c1 = cnt[i0 + 1];
    int ts = c0 + c1;
    sd[tid] = ts;
    __syncthreads();
    for (int off = 1; off < 256; off <<= 1) {
        int t = (tid >= off) ? sd[tid - off] : 0;
        __syncthreads();
        sd[tid] += t;
        __syncthreads();
    }
    int ex = sd[tid] - ts;
    exc[i0] = ex;       exc[i0 + 1] = ex + c0;
    cur[i0] = ex;       cur[i0 + 1] = ex + c0;
    if (c0 > 0) bb[i0] = atomicAdd(&gCursor[i0], c0);
    if (c1 > 0) bb[i0 + 1] = atomicAdd(&gCursor[i0 + 1], c1);
    __syncthreads();
#pragma unroll
    for (int q = 0; q < P1T / 256; ++q) {
        int li = q * 256 + tid;
        if (li < m) {
            int b = b8[q];
            int pos = atomicAdd(&cur[b], 1);
            stage[pos] = pk8[q];
            stgb[pos] = (unsigned short)b;
        }
    }
    __syncthreads();
#pragma unroll
    for (int q = 0; q < P1T / 256; ++q) {
        int p = q * 256 + tid;
        if (p < m) {
            int b = stgb[p];
            pkbuf[bucketStart[b] + bb[b] + (p - exc[b])] = stage[p];
        }
    }
}

// p2: per-superblock counting sort -> csr padded to x8 per row, values src<<5;
// 33-entry row bounds per gather block; dinv/xs by-product.
__global__ __launch_bounds__(256) void k_p2(int n, const int* __restrict__ bucketStart,
                                            const int* __restrict__ pkbuf,
                                            const float* __restrict__ x,
                                            int* __restrict__ csr,
                                            int* __restrict__ bndRow,
                                            float* __restrict__ dinv,
                                            float* __restrict__ xs) {
    __shared__ int cnt[SBKEYS + 1];
    __shared__ int sd[256];
    __shared__ int padOff[SBS];
    __shared__ int padTotal_s;
    int sb = blockIdx.x, tid = threadIdx.x;
    int r0 = bucketStart[sb], r1 = bucketStart[sb + 1];
    int r0pad = r0 + sb * PADGAP;
    for (int k = tid; k < SBKEYS + 1; k += 256) cnt[k] = 0;
    __syncthreads();
    // phase A: count keys (key = dl*8 + chunk)
    for (int i = r0 + tid; i < r1; i += 256) {
        int w = pkbuf[i];
        int key = ((w >> USH) << 3) | ((w & ((1 << USH) - 1)) >> CSH);
        atomicAdd(&cnt[key], 1);
    }
    __syncthreads();
    // key scan (8 keys/thread, in place)
    int base8 = tid * 8;
    int loc[8]; int s = 0;
#pragma unroll
    for (int j = 0; j < 8; ++j) { loc[j] = cnt[base8 + j]; s += loc[j]; }
    sd[tid] = s;
    __syncthreads();
    for (int off = 1; off < 256; off <<= 1) {
        int t = (tid >= off) ? sd[tid - off] : 0;
        __syncthreads();
        sd[tid] += t;
        __syncthreads();
    }
    int run = sd[tid] - s;
#pragma unroll
    for (int j = 0; j < 8; ++j) { cnt[base8 + j] = run; run += loc[j]; }
    if (tid == 255) cnt[SBKEYS] = run;
    __syncthreads();
    // pad scan: 1 row/thread (pad each row to multiple of 8)
    int lenR = cnt[tid * 8 + 8] - cnt[tid * 8];
    int padR = (-lenR) & 7;
    sd[tid] = padR;
    __syncthreads();
    for (int off = 1; off < 256; off <<= 1) {
        int t = (tid >= off) ? sd[tid - off] : 0;
        __syncthreads();
        sd[tid] += t;
        __syncthreads();
    }
    int pexcl = sd[tid] - padR;
    padOff[tid] = pexcl;
    if (tid == 255) padTotal_s = pexcl + padR;
    __syncthreads();
    // bounds (33/gather-block), dinv/xs, row pads (-> n<<5)
    {
        int dl = tid;
        int gbi = sb * 8 + (dl >> 5);
        int vi = dl & 31;
        int startp = r0pad + cnt[dl * 8] + padOff[dl];
        bndRow[gbi * 33 + vi] = startp;
        if (vi == 0 && dl > 0) bndRow[(gbi - 1) * 33 + 32] = startp;
        int v = sb * SBS + dl;
        if (v < n) {
            float di = 1.0f / sqrtf((float)(lenR + 1));
            dinv[v] = di;
            xs[v] = x[v] * di;
        }
        int ps = r0pad + cnt[dl * 8 + 8] + padOff[dl];
        for (int j = 0; j < padR; ++j) csr[ps + j] = n << 5;
    }
    if (tid == 0) {
        int endp = r0pad + cnt[SBKEYS] + padTotal_s;
        bndRow[(sb * 8 + 7) * 33 + 32] = endp;
    }
    __syncthreads();
    // phase C: place pre-scaled src (cnt doubles as cursor)
    for (int i = r0 + tid; i < r1; i += 256) {
        int w = pkbuf[i];
        int srcv = w & ((1 << USH) - 1);
        int dl = w >> USH;
        int key = (dl << 3) | (srcv >> CSH);
        int pos = atomicAdd(&cnt[key], 1);
        csr[r0pad + pos + padOff[dl]] = srcv << 5;
    }
}

// layer 1 fused (rank-1), persistent wave-per-node; bf16 output
__global__ __launch_bounds__(256, 8) void k_layer1(int n, const int* __restrict__ bndRow,
                                                   const int* __restrict__ csr,
                                                   const float* __restrict__ xs,
                                                   const float* __restrict__ dinv,
                                                   const float* __restrict__ w1,
                                                   const float* __restrict__ b1,
                                                   unsigned short* __restrict__ hs_out) {
    int tid = threadIdx.x;
    int r = tid >> 6, lane = tid & 63;
    float w1r = w1[lane], b1r = b1[lane];
    int wid = blockIdx.x * 4 + r;
    int stride = gridDim.x * 4;
    for (int v = wid; v < n; v += stride) {
        int bi = v >> 5, vi = v & 31;
        int s0 = bndRow[bi * 33 + vi], s1 = bndRow[bi * 33 + vi + 1];
        float acc = 0.f;
        for (int k = s0 + lane; k < s1; k += 64) acc += xs[csr[k] >> 5];  // pads: xs[n]=0
#pragma unroll
        for (int m = 32; m > 0; m >>= 1) acc += __shfl_xor(acc, m, 64);
        float dv = dinv[v];
        float s = (acc + xs[v]) * dv;
        hs_out[(size_t)v * 64 + lane] = f2bf(fmaxf(s * w1r + b1r, 0.f) * dv);
    }
}

// ---- single-row groups-of-8 packed-uint gather + inline GEMM ----
// Rows padded to x8 -> no masks; csr values pre-scaled (src<<5); halves of
// the wave take even/odd edges; 2-deep pipeline across groups.
#define GATHER_CORE                                                            \
    __shared__ float ws[64 * 64];                                              \
    __shared__ float rowl[4][64];                                              \
    __shared__ int bndL[NB + 1];                                               \
    int tid = threadIdx.x;                                                     \
    int lane = tid & 63;                                                       \
    int r = tid >> 6;                                                          \
    int h = lane >> 5;                                                         \
    int fi = lane & 31;                                                        \
    int v0 = blockIdx.x * NB;                                                  \
    const unsigned* hsu = (const unsigned*)hs_in;                              \
    for (int k = tid; k < 64 * 64; k += 256) ws[k] = w[k];                     \
    if (tid < NB + 1) bndL[tid] = bndRow[blockIdx.x * 33 + tid];               \
    float accLo[RPW], accHi[RPW];                                              \
    _Pragma("unroll")                                                          \
    for (int q = 0; q < RPW; ++q) {                                            \
        int v = v0 + q * 4 + r;                                                \
        unsigned sv = (v < n && h == 0) ? hsu[(size_t)v * 32 + fi] : 0u;       \
        accLo[q] = bfLo(sv);                                                   \
        accHi[q] = bfHi(sv);                                                   \
    }                                                                          \
    __syncthreads();                                                           \
    _Pragma("unroll")                                                          \
    for (int q = 0; q < RPW; ++q) {                                            \
        int vi = q * 4 + r;                                                    \
        int p  = __builtin_amdgcn_readfirstlane(bndL[vi]);                     \
        int s1 = __builtin_amdgcn_readfirstlane(bndL[vi + 1]);                 \
        if (p < s1) {                                                          \
            int c0 = csr[p],     c1 = csr[p + 1];                              \
            int c2 = csr[p + 2], c3 = csr[p + 3];                              \
            int c4 = csr[p + 4], c5 = csr[p + 5];                              \
            int c6 = csr[p + 6], c7 = csr[p + 7];                              \
            unsigned g0 = hsu[(h ? c1 : c0) + fi];                             \
            unsigned g1 = hsu[(h ? c3 : c2) + fi];                             \
            unsigned g2 = hsu[(h ? c5 : c4) + fi];                             \
            unsigned g3 = hsu[(h ? c7 : c6) + fi];                             \
            p += 8;                                                            \
            while (p < s1) {                                                   \
                int d0 = csr[p],     d1 = csr[p + 1];                          \
                int d2 = csr[p + 2], d3 = csr[p + 3];                          \
                int d4 = csr[p + 4], d5 = csr[p + 5];                          \
                int d6 = csr[p + 6], d7 = csr[p + 7];                          \
                unsigned n0 = hsu[(h ? d1 : d0) + fi];                         \
                unsigned n1 = hsu[(h ? d3 : d2) + fi];                         \
                unsigned n2 = hsu[(h ? d5 : d4) + fi];                         \
                unsigned n3 = hsu[(h ? d7 : d6) + fi];                         \
                accLo[q] += (bfLo(g0) + bfLo(g1)) + (bfLo(g2) + bfLo(g3));     \
                accHi[q] += (bfHi(g0) + bfHi(g1)) + (bfHi(g2) + bfHi(g3));     \
                g0 = n0; g1 = n1; g2 = n2; g3 = n3;                            \
                p += 8;                                                        \
            }                                                                  \
            accLo[q] += (bfLo(g0) + bfLo(g1)) + (bfLo(g2) + bfLo(g3));         \
            accHi[q] += (bfHi(g0) + bfHi(g1)) + (bfHi(g2) + bfHi(g3));         \
        }                                                                      \
    }

__global__ __launch_bounds__(256, 4) void k_gg_mid(int n,
                                                   const int* __restrict__ bndRow,
                                                   const int* __restrict__ csr,
                                                   const unsigned short* __restrict__ hs_in,
                                                   const float* __restrict__ dinv,
                                                   const float* __restrict__ w,
                                                   const float* __restrict__ b,
                                                   unsigned short* __restrict__ hs_out) {
    GATHER_CORE
    float breg = b[lane];
#pragma unroll 1
    for (int q = 0; q < RPW; ++q) {
        int v = v0 + q * 4 + r;
        if (v >= n) continue;
        float dv = dinv[v];
        float lo = accLo[q]; lo += __shfl_xor(lo, 32, 64);
        float hi = accHi[q]; hi += __shfl_xor(hi, 32, 64);
        if (h == 0) {
            rowl[r][2 * fi] = lo * dv;
            rowl[r][2 * fi + 1] = hi * dv;
        }
        float o = breg;
#pragma unroll
        for (int k = 0; k < 64; ++k) o += rowl[r][k] * ws[k * 64 + lane];
        hs_out[(size_t)v * 64 + lane] = f2bf(fmaxf(o, 0.f) * dv);
    }
}

__global__ __launch_bounds__(256, 4) void k_gg_final(int n,
                                                     const int* __restrict__ bndRow,
                                                     const int* __restrict__ csr,
                                                     const unsigned short* __restrict__ hs_in,
                                                     const float* __restrict__ dinv,
                                                     const float* __restrict__ w,
                                                     const float* __restrict__ b,
                                                     const float* __restrict__ fcw,
                                                     float* __restrict__ dots) {
    GATHER_CORE
    float breg = b[lane];
    float freg = fcw[lane];
#pragma unroll 1
    for (int q = 0; q < RPW; ++q) {
        int v = v0 + q * 4 + r;
        if (v >= n) continue;
        float dv = dinv[v];
        float lo = accLo[q]; lo += __shfl_xor(lo, 32, 64);
        float hi = accHi[q]; hi += __shfl_xor(hi, 32, 64);
        if (h == 0) {
            rowl[r][2 * fi] = lo * dv;
            rowl[r][2 * fi + 1] = hi * dv;
        }
        float o = breg;
#pragma unroll
        for (int k = 0; k < 64; ++k) o += rowl[r][k] * ws[k * 64 + lane];
        float val = fmaxf(o, 0.f) * freg;
#pragma unroll
        for (int m = 32; m > 0; m >>= 1) val += __shfl_xor(val, m, 64);
        if (lane == 0) dots[v] = val;
    }
}

// pooled accumulation: LDS-binned segmented reduce over sorted batch
__global__ __launch_bounds__(256) void k_pool(int n, const float* __restrict__ dots,
                                              const int* __restrict__ batch,
                                              float* __restrict__ gsum,
                                              float* __restrict__ gcnt) {
    __shared__ float ls[64], lc[64];
    __shared__ int gmin_s;
    int tid = threadIdx.x;
    int i0 = blockIdx.x * 1024;
    if (tid == 0) gmin_s = batch[i0];
    if (tid < 64) { ls[tid] = 0.f; lc[tid] = 0.f; }
    __syncthreads();
    int gmin = gmin_s;
#pragma unroll
    for (int c = 0; c < 4; ++c) {
        int i = i0 + c * 256 + tid;
        if (i < n) {
            int g = batch[i];
            float d = dots[i];
            int rr = g - gmin;
            if (rr < 64) {
                atomicAdd(&ls[rr], d);
                atomicAdd(&lc[rr], 1.f);
            } else {
                atomicAdd(&gsum[g], d);
                atomicAdd(&gcnt[g], 1.f);
            }
        }
    }
    __syncthreads();
    if (tid < 64 && lc[tid] != 0.f) {
        atomicAdd(&gsum[gmin + tid], ls[tid]);
        atomicAdd(&gcnt[gmin + tid], lc[tid]);
    }
}

__global__ __launch_bounds__(256) void k_out(int g, const float* __restrict__ gsum,
                                             const float* __restrict__ gcnt,
                                             const float* __restrict__ fcb,
                                             float* __restrict__ out) {
    int i = blockIdx.x * blockDim.x + threadIdx.x;
    if (i < g) out[i] = gsum[i] / fmaxf(gcnt[i], 1.f) + fcb[0];
}

extern "C" void kernel_launch(void* const* d_in, const int* in_sizes, int n_in,
                              void* d_out, int out_size, void* d_ws, size_t ws_size,
                              hipStream_t stream) {
    const float* x    = (const float*)d_in[0];
    const int*   ei   = (const int*)d_in[1];
    const int*   batch= (const int*)d_in[2];
    const float* w1   = (const float*)d_in[3];
    const float* b1   = (const float*)d_in[4];
    const float* w2   = (const float*)d_in[5];
    const float* b2   = (const float*)d_in[6];
    const float* w3   = (const float*)d_in[7];
    const float* b3   = (const float*)d_in[8];
    const float* fcw  = (const float*)d_in[9];
    const float* fcb  = (const float*)d_in[10];
    float* out = (float*)d_out;

    const int N = in_sizes[0];           // needs N <= 131072 (17-bit packing)
    const int E = in_sizes[1] / 2;
    const int G = out_size;
    const int H = 64;
    const int nbkt = (N + SBS - 1) / SBS;        // 391 superblocks
    const int NBLK = (N + NB - 1) / NB;          // 3125 gather blocks
    const int NBLKP = nbkt * 8;                  // padded bounds rows (3128)

    const int* src = ei;
    const int* dst = ei + E;

    char* p = (char*)d_ws;
    int*   bucketCnt   = (int*)p; p += WS_ALIGN(sizeof(int) * BKTMAX);
    int*   bucketStart = (int*)p; p += WS_ALIGN(sizeof(int) * (BKTMAX + 1));
    int*   gCursor     = (int*)p; p += WS_ALIGN(sizeof(int) * BKTMAX);
    int*   pkbuf       = (int*)p; p += WS_ALIGN(sizeof(int) * (size_t)E);
    int*   csr         = (int*)p; p += WS_ALIGN(sizeof(int) * ((size_t)E + (size_t)nbkt * PADGAP + 16));
    int*   bndRow      = (int*)p; p += WS_ALIGN(sizeof(int) * (size_t)NBLKP * 33);
    float* dinv        = (float*)p; p += WS_ALIGN(sizeof(float) * N);
    float* xs          = (float*)p; p += WS_ALIGN(sizeof(float) * (N + 1));
    unsigned short* bufA = (unsigned short*)p; p += WS_ALIGN(sizeof(unsigned short) * (size_t)(N + 1) * H);
    unsigned short* bufB = (unsigned short*)p; p += WS_ALIGN(sizeof(unsigned short) * (size_t)(N + 1) * H);
    float* dots        = (float*)p; p += WS_ALIGN(sizeof(float) * N);
    float* gsum        = (float*)p; p += WS_ALIGN(sizeof(float) * G);
    float* gcnt        = (float*)p; p += WS_ALIGN(sizeof(float) * G);

    const int B = 256;
    int gmax     = (G > BKTMAX ? G : BKTMAX);
    int gridZ    = (gmax + B - 1) / B;
    int gridT    = (E + P1T - 1) / P1T;
    int gridG    = (G + B - 1) / B;
    int gridPool = (N + 1023) / 1024;
    int gridPers = 2048;
    if (gridPers * 4 > N) gridPers = (N + 3) / 4;

    k_zero<<<gridZ, B, 0, stream>>>(G, N, bucketCnt, gCursor, xs, bufA, bufB, gsum, gcnt);
    k_cnt1<<<gridT, B, 0, stream>>>(E, dst, bucketCnt);
    k_scanB<<<1, B, 0, stream>>>(nbkt, E, bucketCnt, bucketStart);
    k_p1<<<gridT, B, 0, stream>>>(E, src, dst, bucketStart, gCursor, pkbuf);
    k_p2<<<nbkt, B, 0, stream>>>(N, bucketStart, pkbuf, x, csr, bndRow, dinv, xs);
    // layer 1 (rank-1, fused persistent) -> bf16
    k_layer1<<<gridPers, B, 0, stream>>>(N, bndRow, csr, xs, dinv, w1, b1, bufA);
    // layer 2: fused gather + GEMM(w2) -> bf16
    k_gg_mid<<<NBLK, B, 0, stream>>>(N, bndRow, csr, bufA, dinv, w2, b2, bufB);
    // layer 3: fused gather + GEMM(w3) + fc dot -> dots (f32)
    k_gg_final<<<NBLK, B, 0, stream>>>(N, bndRow, csr, bufB, dinv, w3, b3, fcw, dots);
    // pooling + head
    k_pool<<<gridPool, B, 0, stream>>>(N, dots, batch, gsum, gcnt);
    k_out<<<gridG, B, 0, stream>>>(G, gsum, gcnt, fcb, out);
}

// Round 21
// 325.207 us; speedup vs baseline: 1.0599x; 1.0599x over previous
//
#include <hip/hip_runtime.h>
#include <hip/hip_bf16.h>

// GCN: 3x GCNConv(H=64) + global mean pool + linear head.
// Round 21: REVERT to R18 (empirical best, 326.5us). R19 (x4 padding) was
// neutral; R20 (SBS=256 + x8 groups) regressed the build ~18us with the
// gather unchanged. Four gather variants converged to ~91us (mixed
// VALU-issue/latency equilibrium) — this configuration is the best found.
// Structure: two-pass CSR build (p1 superblock tile-sort, p2 counting sort,
// [row][chunk] order), bf16 feature buffers, whole-row packed-uint gather
// (2 edges/load, 2-deep software pipeline), inline GEMM, LDS-binned pool.

#define WS_ALIGN(x) (((x) + 255) & ~size_t(255))
#define NCHUNK 8
#define CSH 14           // chunk = src >> 14
#define NB 32            // dst rows per gather block
#define RPW (NB / 4)     // rows per wave = 8
#define NBIN (NB * NCHUNK)   // 256
#define USH 17
#define UMASK 0x1FFFF
#define BKTMAX 256
#define SBS 512
#define SBKEYS (SBS * NCHUNK)   // 4096
#define P1T 2048

__device__ __forceinline__ float bf2f(unsigned short h) {
    union { unsigned u; float f; } t;
    t.u = ((unsigned)h) << 16;
    return t.f;
}
__device__ __forceinline__ unsigned short f2bf(float f) {
    union { float f; unsigned u; } t;
    t.f = f;
    unsigned r = t.u + 0x7FFF + ((t.u >> 16) & 1);   // round-to-nearest-even
    return (unsigned short)(r >> 16);
}
__device__ __forceinline__ float bfLo(unsigned v) {
    union { unsigned u; float f; } t;
    t.u = v << 16;
    return t.f;
}
__device__ __forceinline__ float bfHi(unsigned v) {
    union { unsigned u; float f; } t;
    t.u = v & 0xFFFF0000u;
    return t.f;
}

__global__ __launch_bounds__(256) void k_zero(int g, int e, int* bucketCnt,
                                              int* gCursor, int* csr,
                                              float* gsum, float* gcnt) {
    int i = blockIdx.x * blockDim.x + threadIdx.x;
    if (i < BKTMAX) { bucketCnt[i] = 0; gCursor[i] = 0; }
    if (i < g) { gsum[i] = 0.f; gcnt[i] = 0.f; }
    if (i < 4) csr[e + i] = 0;
}

__global__ __launch_bounds__(256) void k_cnt1(int e, const int* __restrict__ dst,
                                              int* __restrict__ bucketCnt) {
    __shared__ int c[BKTMAX];
    int tid = threadIdx.x;
    c[tid] = 0;
    __syncthreads();
    int base = blockIdx.x * P1T;
#pragma unroll
    for (int q = 0; q < P1T / 256; ++q) {
        int i = base + q * 256 + tid;
        if (i < e) atomicAdd(&c[dst[i] >> 9], 1);
    }
    __syncthreads();
    if (c[tid] > 0) atomicAdd(&bucketCnt[tid], c[tid]);
}

__global__ __launch_bounds__(256) void k_scanB(int nbkt, int e,
                                               const int* __restrict__ bucketCnt,
                                               int* __restrict__ bucketStart) {
    __shared__ int sd[256];
    int tid = threadIdx.x;
    int v = (tid < nbkt) ? bucketCnt[tid] : 0;
    sd[tid] = v;
    __syncthreads();
    for (int off = 1; off < 256; off <<= 1) {
        int t = (tid >= off) ? sd[tid - off] : 0;
        __syncthreads();
        sd[tid] += t;
        __syncthreads();
    }
    if (tid < nbkt) bucketStart[tid] = sd[tid] - v;
    if (tid == 0) bucketStart[nbkt] = e;
}

// p1: tile sort by superblock, contiguous run writes of packed words
__global__ __launch_bounds__(256) void k_p1(int e, const int* __restrict__ src,
                                            const int* __restrict__ dst,
                                            const int* __restrict__ bucketStart,
                                            int* __restrict__ gCursor,
                                            int* __restrict__ pkbuf) {
    __shared__ int cnt[BKTMAX], exc[BKTMAX], cur[BKTMAX], bb[BKTMAX];
    __shared__ int sd[256];
    __shared__ int stage[P1T];
    __shared__ unsigned char stgb[P1T];
    int tid = threadIdx.x;
    cnt[tid] = 0;
    __syncthreads();
    int base = blockIdx.x * P1T;
    int m = e - base; if (m > P1T) m = P1T;
    int pk8[P1T / 256];
    int b8[P1T / 256];
#pragma unroll
    for (int q = 0; q < P1T / 256; ++q) {
        int li = q * 256 + tid;
        if (li < m) {
            int d = dst[base + li];
            int s = src[base + li];
            int b = d >> 9;
            b8[q] = b;
            pk8[q] = ((d & (SBS - 1)) << USH) | s;
            atomicAdd(&cnt[b], 1);
        }
    }
    __syncthreads();
    int cv = cnt[tid];
    sd[tid] = cv;
    __syncthreads();
    for (int off = 1; off < 256; off <<= 1) {
        int t = (tid >= off) ? sd[tid - off] : 0;
        __syncthreads();
        sd[tid] += t;
        __syncthreads();
    }
    exc[tid] = sd[tid] - cv;
    cur[tid] = sd[tid] - cv;
    if (cv > 0) bb[tid] = atomicAdd(&gCursor[tid], cv);
    __syncthreads();
#pragma unroll
    for (int q = 0; q < P1T / 256; ++q) {
        int li = q * 256 + tid;
        if (li < m) {
            int b = b8[q];
            int pos = atomicAdd(&cur[b], 1);
            stage[pos] = pk8[q];
            stgb[pos] = (unsigned char)b;
        }
    }
    __syncthreads();
#pragma unroll
    for (int q = 0; q < P1T / 256; ++q) {
        int p = q * 256 + tid;
        if (p < m) {
            int b = stgb[p];
            pkbuf[bucketStart[b] + bb[b] + (p - exc[b])] = stage[p];
        }
    }
}

// p2: per-superblock counting sort -> csr [row][chunk] + bounds + dinv/xs
__global__ __launch_bounds__(256) void k_p2(int n, const int* __restrict__ bucketStart,
                                            const int* __restrict__ pkbuf,
                                            const float* __restrict__ x,
                                            int* __restrict__ csr,
                                            int* __restrict__ boundsG,
                                            float* __restrict__ dinv,
                                            float* __restrict__ xs) {
    __shared__ int cnt[SBKEYS + 1];
    __shared__ int sd[256];
    int sb = blockIdx.x, tid = threadIdx.x;
    int r0 = bucketStart[sb], r1 = bucketStart[sb + 1];
    for (int k = tid; k < SBKEYS + 1; k += 256) cnt[k] = 0;
    __syncthreads();
    for (int i = r0 + tid; i < r1; i += 256) {
        int w = pkbuf[i];
        int key = ((w >> USH) << 3) | ((w & UMASK) >> CSH);
        atomicAdd(&cnt[key], 1);
    }
    __syncthreads();
    int base16 = tid * 16;
    int loc[16]; int s = 0;
#pragma unroll
    for (int j = 0; j < 16; ++j) { loc[j] = cnt[base16 + j]; s += loc[j]; }
    sd[tid] = s;
    __syncthreads();
    for (int off = 1; off < 256; off <<= 1) {
        int t = (tid >= off) ? sd[tid - off] : 0;
        __syncthreads();
        sd[tid] += t;
        __syncthreads();
    }
    int run = sd[tid] - s;
#pragma unroll
    for (int j = 0; j < 16; ++j) { cnt[base16 + j] = run; run += loc[j]; }
    if (tid == 255) cnt[SBKEYS] = run;
    __syncthreads();
    for (int k = tid; k < SBKEYS; k += 256) {
        int bi = sb * 16 + (k >> 8);
        boundsG[(size_t)bi * (NBIN + 1) + (k & 255)] = r0 + cnt[k];
    }
    if (tid < 16)
        boundsG[(size_t)(sb * 16 + tid) * (NBIN + 1) + NBIN] = r0 + cnt[(tid + 1) * 256];
    for (int dl = tid; dl < SBS; dl += 256) {
        int v = sb * SBS + dl;
        if (v < n) {
            int deg = cnt[dl * 8 + 8] - cnt[dl * 8] + 1;
            float di = 1.0f / sqrtf((float)deg);
            dinv[v] = di;
            xs[v] = x[v] * di;
        }
    }
    __syncthreads();
    for (int i = r0 + tid; i < r1; i += 256) {
        int w = pkbuf[i];
        int srcv = w & UMASK;
        int key = ((w >> USH) << 3) | (srcv >> CSH);
        int pos = atomicAdd(&cnt[key], 1);
        csr[r0 + pos] = srcv;
    }
}

// layer 1 fused (rank-1), persistent wave-per-node; bf16 output
__global__ __launch_bounds__(256, 8) void k_layer1(int n, const int* __restrict__ boundsG,
                                                   const int* __restrict__ csr,
                                                   const float* __restrict__ xs,
                                                   const float* __restrict__ dinv,
                                                   const float* __restrict__ w1,
                                                   const float* __restrict__ b1,
                                                   unsigned short* __restrict__ hs_out) {
    int tid = threadIdx.x;
    int r = tid >> 6, lane = tid & 63;
    float w1r = w1[lane], b1r = b1[lane];
    int wid = blockIdx.x * 4 + r;
    int stride = gridDim.x * 4;
    for (int v = wid; v < n; v += stride) {
        int bi = v / NB, vi = v & (NB - 1);
        size_t base = (size_t)bi * (NBIN + 1) + vi * NCHUNK;
        int s0 = boundsG[base], s1 = boundsG[base + NCHUNK];
        float acc = 0.f;
        for (int k = s0 + lane; k < s1; k += 64) acc += xs[csr[k]];
#pragma unroll
        for (int m = 32; m > 0; m >>= 1) acc += __shfl_xor(acc, m, 64);
        float dv = dinv[v];
        float s = (acc + xs[v]) * dv;
        hs_out[(size_t)v * 64 + lane] = f2bf(fmaxf(s * w1r + b1r, 0.f) * dv);
    }
}

// ---- packed-uint whole-row gather (2 edges/load) + inline GEMM ----
// h = lane>>5 selects even/odd edges; fi = lane&31 is the uint feature pair.
// accLo/accHi per row-slot; halves merged by shfl_xor(32) at epilogue.
#define GATHER_CORE                                                            \
    __shared__ float ws[64 * 64];                                              \
    __shared__ float rowl[4][64];                                              \
    __shared__ int bndL[NBIN + 1];                                             \
    int tid = threadIdx.x;                                                     \
    int lane = tid & 63;                                                       \
    int r = tid >> 6;                                                          \
    int h = lane >> 5;                                                         \
    int fi = lane & 31;                                                        \
    int v0 = blockIdx.x * NB;                                                  \
    const unsigned* hsu = (const unsigned*)hs_in;                              \
    for (int k = tid; k < 64 * 64; k += 256) ws[k] = w[k];                     \
    for (int i = tid; i < NBIN + 1; i += 256)                                  \
        bndL[i] = boundsG[(size_t)blockIdx.x * (NBIN + 1) + i];                \
    float accLo[RPW], accHi[RPW];                                              \
    _Pragma("unroll")                                                          \
    for (int q = 0; q < RPW; ++q) {                                            \
        int v = v0 + q * 4 + r;                                                \
        unsigned sv = (v < n && h == 0) ? hsu[(size_t)v * 32 + fi] : 0u;       \
        accLo[q] = bfLo(sv);                                                   \
        accHi[q] = bfHi(sv);                                                   \
    }                                                                          \
    __syncthreads();                                                           \
    _Pragma("unroll")                                                          \
    for (int t = 0; t < RPW / 2; ++t) {                                        \
        int viA = (2 * t) * 4 + r;                                             \
        int viB = (2 * t + 1) * 4 + r;                                         \
        int ba = __builtin_amdgcn_readfirstlane(bndL[viA * NCHUNK]);           \
        int a1 = __builtin_amdgcn_readfirstlane(bndL[viA * NCHUNK + NCHUNK]);  \
        int bb = __builtin_amdgcn_readfirstlane(bndL[viB * NCHUNK]);           \
        int b1_ = __builtin_amdgcn_readfirstlane(bndL[viB * NCHUNK + NCHUNK]); \
        int pa = (a1 - ba > 0) ? ba : bb;                                      \
        int pb = (b1_ - bb > 0) ? bb : ba;                                     \
        int uA0 = csr[pa], uA1 = csr[pa + 1], uA2 = csr[pa + 2], uA3 = csr[pa + 3]; \
        int uB0 = csr[pb], uB1 = csr[pb + 1], uB2 = csr[pb + 2], uB3 = csr[pb + 3]; \
        unsigned gA01 = hsu[(size_t)(h ? uA1 : uA0) * 32 + fi];                \
        unsigned gA23 = hsu[(size_t)(h ? uA3 : uA2) * 32 + fi];                \
        unsigned gB01 = hsu[(size_t)(h ? uB1 : uB0) * 32 + fi];                \
        unsigned gB23 = hsu[(size_t)(h ? uB3 : uB2) * 32 + fi];                \
        while (ba < a1 || bb < b1_) {                                          \
            int na = ba + 4, nb = bb + 4;                                      \
            int pa2 = (a1 - na > 0) ? na : ((b1_ - nb > 0) ? nb : pa);         \
            int pb2 = (b1_ - nb > 0) ? nb : ((a1 - na > 0) ? na : pb);         \
            int vA0 = csr[pa2], vA1 = csr[pa2 + 1], vA2 = csr[pa2 + 2], vA3 = csr[pa2 + 3]; \
            int vB0 = csr[pb2], vB1 = csr[pb2 + 1], vB2 = csr[pb2 + 2], vB3 = csr[pb2 + 3]; \
            unsigned nA01 = hsu[(size_t)(h ? vA1 : vA0) * 32 + fi];            \
            unsigned nA23 = hsu[(size_t)(h ? vA3 : vA2) * 32 + fi];            \
            unsigned nB01 = hsu[(size_t)(h ? vB1 : vB0) * 32 + fi];            \
            unsigned nB23 = hsu[(size_t)(h ? vB3 : vB2) * 32 + fi];            \
            int remA = a1 - ba, remB = b1_ - bb;                               \
            float mA0 = (remA > h) ? 1.f : 0.f;                                \
            float mA1 = (remA > 2 + h) ? 1.f : 0.f;                            \
            float mB0 = (remB > h) ? 1.f : 0.f;                                \
            float mB1 = (remB > 2 + h) ? 1.f : 0.f;                            \
            accLo[2 * t]     += bfLo(gA01) * mA0 + bfLo(gA23) * mA1;           \
            accHi[2 * t]     += bfHi(gA01) * mA0 + bfHi(gA23) * mA1;           \
            accLo[2 * t + 1] += bfLo(gB01) * mB0 + bfLo(gB23) * mB1;           \
            accHi[2 * t + 1] += bfHi(gB01) * mB0 + bfHi(gB23) * mB1;           \
            gA01 = nA01; gA23 = nA23; gB01 = nB01; gB23 = nB23;                \
            pa = pa2; pb = pb2;                                                \
            ba = na; bb = nb;                                                  \
        }                                                                      \
    }

__global__ __launch_bounds__(256, 4) void k_gg_mid(int n,
                                                   const int* __restrict__ boundsG,
                                                   const int* __restrict__ csr,
                                                   const unsigned short* __restrict__ hs_in,
                                                   const float* __restrict__ dinv,
                                                   const float* __restrict__ w,
                                                   const float* __restrict__ b,
                                                   unsigned short* __restrict__ hs_out) {
    GATHER_CORE
    float breg = b[lane];
#pragma unroll 1
    for (int q = 0; q < RPW; ++q) {
        int v = v0 + q * 4 + r;
        if (v >= n) continue;
        float dv = dinv[v];
        float lo = accLo[q]; lo += __shfl_xor(lo, 32, 64);
        float hi = accHi[q]; hi += __shfl_xor(hi, 32, 64);
        if (h == 0) {
            rowl[r][2 * fi] = lo * dv;
            rowl[r][2 * fi + 1] = hi * dv;
        }
        float o = breg;
#pragma unroll
        for (int k = 0; k < 64; ++k) o += rowl[r][k] * ws[k * 64 + lane];
        hs_out[(size_t)v * 64 + lane] = f2bf(fmaxf(o, 0.f) * dv);
    }
}

__global__ __launch_bounds__(256, 4) void k_gg_final(int n,
                                                     const int* __restrict__ boundsG,
                                                     const int* __restrict__ csr,
                                                     const unsigned short* __restrict__ hs_in,
                                                     const float* __restrict__ dinv,
                                                     const float* __restrict__ w,
                                                     const float* __restrict__ b,
                                                     const float* __restrict__ fcw,
                                                     float* __restrict__ dots) {
    GATHER_CORE
    float breg = b[lane];
    float freg = fcw[lane];
#pragma unroll 1
    for (int q = 0; q < RPW; ++q) {
        int v = v0 + q * 4 + r;
        if (v >= n) continue;
        float dv = dinv[v];
        float lo = accLo[q]; lo += __shfl_xor(lo, 32, 64);
        float hi = accHi[q]; hi += __shfl_xor(hi, 32, 64);
        if (h == 0) {
            rowl[r][2 * fi] = lo * dv;
            rowl[r][2 * fi + 1] = hi * dv;
        }
        float o = breg;
#pragma unroll
        for (int k = 0; k < 64; ++k) o += rowl[r][k] * ws[k * 64 + lane];
        float val = fmaxf(o, 0.f) * freg;
#pragma unroll
        for (int m = 32; m > 0; m >>= 1) val += __shfl_xor(val, m, 64);
        if (lane == 0) dots[v] = val;
    }
}

// pooled accumulation: LDS-binned segmented reduce over sorted batch
__global__ __launch_bounds__(256) void k_pool(int n, const float* __restrict__ dots,
                                              const int* __restrict__ batch,
                                              float* __restrict__ gsum,
                                              float* __restrict__ gcnt) {
    __shared__ float ls[64], lc[64];
    __shared__ int gmin_s;
    int tid = threadIdx.x;
    int i0 = blockIdx.x * 1024;
    if (tid == 0) gmin_s = batch[i0];
    if (tid < 64) { ls[tid] = 0.f; lc[tid] = 0.f; }
    __syncthreads();
    int gmin = gmin_s;
#pragma unroll
    for (int c = 0; c < 4; ++c) {
        int i = i0 + c * 256 + tid;
        if (i < n) {
            int g = batch[i];
            float d = dots[i];
            int rr = g - gmin;
            if (rr < 64) {
                atomicAdd(&ls[rr], d);
                atomicAdd(&lc[rr], 1.f);
            } else {
                atomicAdd(&gsum[g], d);
                atomicAdd(&gcnt[g], 1.f);
            }
        }
    }
    __syncthreads();
    if (tid < 64 && lc[tid] != 0.f) {
        atomicAdd(&gsum[gmin + tid], ls[tid]);
        atomicAdd(&gcnt[gmin + tid], lc[tid]);
    }
}

__global__ __launch_bounds__(256) void k_out(int g, const float* __restrict__ gsum,
                                             const float* __restrict__ gcnt,
                                             const float* __restrict__ fcb,
                                             float* __restrict__ out) {
    int i = blockIdx.x * blockDim.x + threadIdx.x;
    if (i < g) out[i] = gsum[i] / fmaxf(gcnt[i], 1.f) + fcb[0];
}

extern "C" void kernel_launch(void* const* d_in, const int* in_sizes, int n_in,
                              void* d_out, int out_size, void* d_ws, size_t ws_size,
                              hipStream_t stream) {
    const float* x    = (const float*)d_in[0];
    const int*   ei   = (const int*)d_in[1];
    const int*   batch= (const int*)d_in[2];
    const float* w1   = (const float*)d_in[3];
    const float* b1   = (const float*)d_in[4];
    const float* w2   = (const float*)d_in[5];
    const float* b2   = (const float*)d_in[6];
    const float* w3   = (const float*)d_in[7];
    const float* b3   = (const float*)d_in[8];
    const float* fcw  = (const float*)d_in[9];
    const float* fcb  = (const float*)d_in[10];
    float* out = (float*)d_out;

    const int N = in_sizes[0];           // needs N <= 131072 (17-bit packing)
    const int E = in_sizes[1] / 2;
    const int G = out_size;
    const int H = 64;
    const int nbkt = (N + SBS - 1) / SBS;        // 196 superblocks
    const int NBLK = (N + NB - 1) / NB;          // 3125 gather blocks
    const int NBLKP = nbkt * 16;                 // padded bounds rows

    const int* src = ei;
    const int* dst = ei + E;

    char* p = (char*)d_ws;
    int*   bucketCnt   = (int*)p; p += WS_ALIGN(sizeof(int) * BKTMAX);
    int*   bucketStart = (int*)p; p += WS_ALIGN(sizeof(int) * (BKTMAX + 1));
    int*   gCursor     = (int*)p; p += WS_ALIGN(sizeof(int) * BKTMAX);
    int*   pkbuf       = (int*)p; p += WS_ALIGN(sizeof(int) * (size_t)E);
    int*   csr         = (int*)p; p += WS_ALIGN(sizeof(int) * ((size_t)E + 4));
    int*   boundsG     = (int*)p; p += WS_ALIGN(sizeof(int) * (size_t)NBLKP * (NBIN + 1));
    float* dinv        = (float*)p; p += WS_ALIGN(sizeof(float) * N);
    float* xs          = (float*)p; p += WS_ALIGN(sizeof(float) * (N + 1));
    unsigned short* bufA = (unsigned short*)p; p += WS_ALIGN(sizeof(unsigned short) * (size_t)(N + 1) * H);
    unsigned short* bufB = (unsigned short*)p; p += WS_ALIGN(sizeof(unsigned short) * (size_t)(N + 1) * H);
    float* dots        = (float*)p; p += WS_ALIGN(sizeof(float) * N);
    float* gsum        = (float*)p; p += WS_ALIGN(sizeof(float) * G);
    float* gcnt        = (float*)p; p += WS_ALIGN(sizeof(float) * G);

    const int B = 256;
    int gridZ    = ((G > BKTMAX ? G : BKTMAX) + B - 1) / B;
    int gridT    = (E + P1T - 1) / P1T;
    int gridG    = (G + B - 1) / B;
    int gridPool = (N + 1023) / 1024;
    int gridPers = 2048;
    if (gridPers * 4 > N) gridPers = (N + 3) / 4;

    k_zero<<<gridZ, B, 0, stream>>>(G, E, bucketCnt, gCursor, csr, gsum, gcnt);
    k_cnt1<<<gridT, B, 0, stream>>>(E, dst, bucketCnt);
    k_scanB<<<1, B, 0, stream>>>(nbkt, E, bucketCnt, bucketStart);
    k_p1<<<gridT, B, 0, stream>>>(E, src, dst, bucketStart, gCursor, pkbuf);
    k_p2<<<nbkt, B, 0, stream>>>(N, bucketStart, pkbuf, x, csr, boundsG, dinv, xs);
    // layer 1 (rank-1, fused persistent) -> bf16
    k_layer1<<<gridPers, B, 0, stream>>>(N, boundsG, csr, xs, dinv, w1, b1, bufA);
    // layer 2: fused gather + GEMM(w2) -> bf16
    k_gg_mid<<<NBLK, B, 0, stream>>>(N, boundsG, csr, bufA, dinv, w2, b2, bufB);
    // layer 3: fused gather + GEMM(w3) + fc dot -> dots (f32)
    k_gg_final<<<NBLK, B, 0, stream>>>(N, boundsG, csr, bufB, dinv, w3, b3, fcw, dots);
    // pooling + head
    k_pool<<<gridPool, B, 0, stream>>>(N, dots, batch, gsum, gcnt);
    k_out<<<gridG, B, 0, stream>>>(G, gsum, gcnt, fcb, out);
}